// Round 6
// baseline (237.519 us; speedup 1.0000x reference)
//
#include <hip/hip_runtime.h>

#define NN 100000     // nodes
#define NE 1600000    // edges
#define NG 512        // graphs
#define C_H1 64
#define C_H2 128
#define C_OUT 2

#define MM2_BLOCKS ((NN + 127) / 128)                 // 782 real tiles (128 nodes)
#define MM2_PAD 784                                   // padded to %8==0 for XCD bijection
#define NB ((NN + 255) >> 8)                          // 391 dst-buckets of 256 nodes
#define PCHUNKS 512                                   // partition chunks
#define PCHUNK_E (NE / PCHUNKS)                       // 3125 edges per chunk

// ---------------- radix partition phase 1: per-chunk bucket histograms -----------
__global__ void k_hist(const int* __restrict__ ei, int* __restrict__ hist) {
    __shared__ int lh[NB];
    int tid = threadIdx.x;
    int blk = blockIdx.x;
    for (int i = tid; i < NB; i += 256) lh[i] = 0;
    __syncthreads();
    int base = blk * PCHUNK_E;
    for (int e = base + tid; e < base + PCHUNK_E; e += 256)
        atomicAdd(&lh[ei[NE + e] >> 8], 1);
    __syncthreads();
    for (int i = tid; i < NB; i += 256) hist[i * PCHUNKS + blk] = lh[i];
}

// ---------------- phase 2a: per-bucket scan over chunks (bucket-relative) --------
__global__ void k_colscan0(const int* __restrict__ hist, int* __restrict__ offs,
                           int* __restrict__ btot) {
    __shared__ int sh[256];
    int b = blockIdx.x;
    int tid = threadIdx.x;
    int v0 = hist[b * PCHUNKS + 2 * tid];
    int v1 = hist[b * PCHUNKS + 2 * tid + 1];
    sh[tid] = v0 + v1;
    __syncthreads();
    for (int off = 1; off < 256; off <<= 1) {
        int v = (tid >= off) ? sh[tid - off] : 0;
        __syncthreads();
        sh[tid] += v;
        __syncthreads();
    }
    int base = (tid == 0) ? 0 : sh[tid - 1];
    offs[b * PCHUNKS + 2 * tid]     = base;
    offs[b * PCHUNKS + 2 * tid + 1] = base + v0;
    if (tid == 255) btot[b] = sh[255];
}

// ---------------- phase 2b: exclusive scan of 391 bucket totals ------------------
__global__ void k_bbase(const int* __restrict__ btot, int* __restrict__ bbase,
                        int* __restrict__ row_ptr) {
    __shared__ int sh[256];
    int tid = threadIdx.x;
    int v0 = (2 * tid     < NB) ? btot[2 * tid]     : 0;
    int v1 = (2 * tid + 1 < NB) ? btot[2 * tid + 1] : 0;
    sh[tid] = v0 + v1;
    __syncthreads();
    for (int off = 1; off < 256; off <<= 1) {
        int v = (tid >= off) ? sh[tid - off] : 0;
        __syncthreads();
        sh[tid] += v;
        __syncthreads();
    }
    int base = (tid == 0) ? 0 : sh[tid - 1];
    if (2 * tid     < NB) bbase[2 * tid]     = base;
    if (2 * tid + 1 < NB) bbase[2 * tid + 1] = base + v0;
    if (tid == 255) { bbase[NB] = sh[255]; row_ptr[NN] = sh[255]; }   // == NE
}

// ---------------- phase 3: scatter via LDS cursors (no global atomics) -----------
__global__ void k_scatterA(const int* __restrict__ ei, const int* __restrict__ offs,
                           const int* __restrict__ bbase, int2* __restrict__ ed2) {
    __shared__ int lcur[NB];
    int tid = threadIdx.x;
    int blk = blockIdx.x;
    for (int i = tid; i < NB; i += 256) lcur[i] = bbase[i] + offs[i * PCHUNKS + blk];
    __syncthreads();
    int base = blk * PCHUNK_E;
    for (int e = base + tid; e < base + PCHUNK_E; e += 256) {
        int s = ei[e], d = ei[NE + e];
        int pos = atomicAdd(&lcur[d >> 8], 1);     // LDS atomic, low contention
        int2 v; v.x = s; v.y = d;
        ed2[pos] = v;
    }
}

// ---------------- B1: bucket-local degree -> dinv + row_ptr (no global atomics) --
__global__ void k_B1(const int2* __restrict__ ed2, const int* __restrict__ bbase,
                     float* __restrict__ dinv, int* __restrict__ row_ptr) {
    __shared__ int ldeg[256];
    __shared__ int sh[256];
    int b = blockIdx.x;
    int tid = threadIdx.x;
    int lo = b << 8;
    ldeg[tid] = 0;
    __syncthreads();
    int beg = bbase[b], end = bbase[b + 1];
    for (int j = beg + tid; j < end; j += 256)
        atomicAdd(&ldeg[ed2[j].y - lo], 1);
    __syncthreads();
    int d = ldeg[tid];
    int node = lo + tid;
    if (node < NN) dinv[node] = rsqrtf((float)d + 1.0f);
    sh[tid] = d;
    __syncthreads();
    for (int off = 1; off < 256; off <<= 1) {
        int v = (tid >= off) ? sh[tid - off] : 0;
        __syncthreads();
        sh[tid] += v;
        __syncthreads();
    }
    int excl = beg + ((tid == 0) ? 0 : sh[tid - 1]);
    if (node < NN) row_ptr[node] = excl;
}

// ---------------- repack x to float4 rows (16B gathers downstream) ---------------
__global__ void k_x4(const float* __restrict__ x, float4* __restrict__ x4) {
    int n = blockIdx.x * blockDim.x + threadIdx.x;
    if (n >= NN) return;
    float4 v; v.x = x[n * 3]; v.y = x[n * 3 + 1]; v.z = x[n * 3 + 2]; v.w = 0.f;
    x4[n] = v;
}

// ---------------- scatter pass B + fused layer-1 aggregation ---------------------
// ed is just the src index (4B): nrm is recomputed in k_edge1 from
// aggx4[src].w (= dinv[src], packed here) * dinv[dst] -- identical fp multiply,
// so agg1 stays bitwise identical while ed traffic halves.
__global__ void k_scatterB(const int* __restrict__ row_ptr, const int2* __restrict__ ed2,
                           const float* __restrict__ dinv, const float4* __restrict__ x4,
                           int* __restrict__ ed, float4* __restrict__ aggx4) {
    __shared__ int   lcur[256];
    __shared__ float ldin[256];
    __shared__ float lax[256 * 3];
    int b = blockIdx.x;
    int lo = b << 8;
    int tid = threadIdx.x;
    int node = lo + tid;
    if (node <= NN) lcur[tid] = row_ptr[node < NN ? node : NN];
    else            lcur[tid] = 0;
    ldin[tid] = (node < NN) ? dinv[node] : 0.f;
    lax[tid] = 0.f; lax[256 + tid] = 0.f; lax[512 + tid] = 0.f;
    __syncthreads();
    int seg_beg = row_ptr[lo];
    int hi = lo + 256; if (hi > NN) hi = NN;
    int seg_end = row_ptr[hi];
    for (int j = seg_beg + tid; j < seg_end; j += 256) {
        int2 sd = ed2[j];
        int local = sd.y - lo;
        int pos = atomicAdd(&lcur[local], 1);
        float nrm = dinv[sd.x] * ldin[local];
        ed[pos] = sd.x;                                // 4B scatter
        float4 xs = x4[sd.x];                          // 16B gather, L2-hot (1.6MB)
        atomicAdd(&lax[local],       nrm * xs.x);      // ds_add_f32
        atomicAdd(&lax[256 + local], nrm * xs.y);
        atomicAdd(&lax[512 + local], nrm * xs.z);
    }
    __syncthreads();
    if (node < NN) {
        float di = ldin[tid];
        float s2 = di * di;
        float4 xs = x4[node];
        float4 a;
        a.x = lax[tid]       + s2 * xs.x;
        a.y = lax[256 + tid] + s2 * xs.y;
        a.z = lax[512 + tid] + s2 * xs.z;
        a.w = di;                                      // pack dinv for k_edge1
        aggx4[node] = a;
    }
}

// ---------------- layer 2 aggregate via on-the-fly h1 recompute ------------------
// v9: XCD-affinity swizzle. agg1 tile T (128 nodes) is written ONLY by blocks on
// XCD T%8 (empirical mapping: blockIdx%8). k_mm2pool reads tile T from a block on
// the SAME XCD -> agg1 reads become local-L2 hits instead of remote-dirty misses
// (v5-v8 post-mortem: FETCH 12.9MB = half of agg1 missed L2; ~1800cy stalls).
// Grid padded to 784*32 blocks so the (r=b%8, j, sub) -> T=r+8j map is bijective.
__global__ void k_edge1(const int* __restrict__ row_ptr, const int* __restrict__ ed,
                        const float4* __restrict__ aggx4,
                        const float* __restrict__ W1, const float* __restrict__ b1,
                        float* __restrict__ agg1) {
    __shared__ float4 lp[256];                        // 64 per wave
    int bsw = blockIdx.x;
    int r   = bsw & 7;
    int idx = bsw >> 3;                               // 0..3135
    int T   = r + ((idx >> 5) << 3);                  // tile 0..783, T%8 == r
    int nb  = (T << 5) + (idx & 31);                  // node-block (4 nodes)
    int n   = (nb << 2) + (threadIdx.x >> 6);         // this wave's node
    if (n >= NN) return;                              // wave-uniform guard
    int c = threadIdx.x & 63;
    int lane = threadIdx.x & 63;
    int wbase = threadIdx.x & 192;                    // wave's LDS base (0,64,128,192)

    float w0 = W1[c], w1 = W1[64 + c], w2 = W1[128 + c], bb = b1[c];
    float4 an = aggx4[n];                             // wave-uniform
    float di = an.w;                                  // dinv[n], packed by scatterB
    float hself = fmaxf(fmaf(an.x, w0, fmaf(an.y, w1, fmaf(an.z, w2, bb))), 0.f);
    float acc = di * di * hself;

    int beg = row_ptr[n], end = row_ptr[n + 1];
    for (int base = beg; base < end; base += 64) {
        int m = end - base; if (m > 64) m = 64;
        if (lane < m) {
            int s = ed[base + lane];                  // coalesced 4B
            float4 ax = aggx4[s];                     // random 16B, L2-hot
            float4 p; p.x = ax.x; p.y = ax.y; p.z = ax.z; p.w = ax.w * di;  // nrm
            lp[wbase + lane] = p;
        }
        int e = 0;
        for (; e + 3 < m; e += 4) {
            float4 p0 = lp[wbase + e];
            float4 p1 = lp[wbase + e + 1];
            float4 p2 = lp[wbase + e + 2];
            float4 p3 = lp[wbase + e + 3];
            float h0  = fmaxf(fmaf(p0.x, w0, fmaf(p0.y, w1, fmaf(p0.z, w2, bb))), 0.f);
            float h1v = fmaxf(fmaf(p1.x, w0, fmaf(p1.y, w1, fmaf(p1.z, w2, bb))), 0.f);
            float h2v = fmaxf(fmaf(p2.x, w0, fmaf(p2.y, w1, fmaf(p2.z, w2, bb))), 0.f);
            float h3v = fmaxf(fmaf(p3.x, w0, fmaf(p3.y, w1, fmaf(p3.z, w2, bb))), 0.f);
            acc = fmaf(p0.w, h0, acc);
            acc = fmaf(p1.w, h1v, acc);
            acc = fmaf(p2.w, h2v, acc);
            acc = fmaf(p3.w, h3v, acc);
        }
        for (; e < m; ++e) {
            float4 p = lp[wbase + e];
            float h = fmaxf(fmaf(p.x, w0, fmaf(p.y, w1, fmaf(p.z, w2, bb))), 0.f);
            acc = fmaf(p.w, h, acc);
        }
    }
    agg1[n * 64 + c] = acc;   // NO bias/relu: h2 = relu(agg1 @ W2 + b2)
}

// ---------------- fused register-tiled GEMM + pool (v9: XCD-matched reader) -------
// Core = v7 (barrier-free, direct-global A, 8x8 micro-tile; v8's prefetch reverted
// -- hipcc sank the loads and added 512 v_movs, 47->55us). Block b -> tile
// T=(b%8)+8*(b/8): reader XCD (b%8) == writer XCD (T%8, see k_edge1) -> agg1
// tile is local-L2 resident (3.2MB/XCD slice of 25.6MB).
__global__ __launch_bounds__(256)
void k_mm2pool(const float* __restrict__ agg1, const float* __restrict__ W2,
               const float* __restrict__ b2, const int* __restrict__ batch,
               float* __restrict__ pooled) {
    int bsw = blockIdx.x;
    int bx  = (bsw & 7) + ((bsw >> 3) << 3 == 0 ? 0 : ((bsw >> 3) << 3)); // T = r + 8*(b/8)
    bx = (bsw & 7) + ((bsw >> 3) << 3);
    if (bx >= MM2_BLOCKS) return;

    __shared__ float wt[C_H1 * C_H2];     // 32 KiB: full W2
    __shared__ float lpool[4 * C_H2];     // 2 KiB
    int tid = threadIdx.x;

    {
        const float4* w4 = (const float4*)W2;
        float4* wl = (float4*)wt;
        for (int i = tid; i < (C_H1 * C_H2) / 4; i += 256) wl[i] = w4[i];
        for (int i = tid; i < 4 * C_H2; i += 256) lpool[i] = 0.f;
    }
    __syncthreads();                       // the ONLY pre-epilogue barrier

    int tx = tid & 15;            // channel group
    int my = tid >> 4;            // node lane: rows my, my+16, ..., my+112
    int c0 = tx * 4;              // low ch group c0..c0+3; high group 64+c0..+3

    float acc[8][8];
#pragma unroll
    for (int i = 0; i < 8; ++i)
#pragma unroll
        for (int j = 0; j < 8; ++j) acc[i][j] = 0.f;

    const float* ab = agg1 + (size_t)bx * 128 * C_H1;

#pragma unroll 1
    for (int k0 = 0; k0 < C_H1; k0 += 4) {
        float4 wfA[4], wfB[4];
#pragma unroll
        for (int kk = 0; kk < 4; ++kk) {
            wfA[kk] = *(const float4*)&wt[(k0 + kk) * C_H2 + c0];
            wfB[kk] = *(const float4*)&wt[(k0 + kk) * C_H2 + 64 + c0];
        }
#pragma unroll
        for (int i = 0; i < 8; ++i) {
            float4 af = *(const float4*)(ab + (my + i * 16) * C_H1 + k0);  // local-L2
#pragma unroll
            for (int kk = 0; kk < 4; ++kk) {
                float a = (kk == 0) ? af.x : (kk == 1) ? af.y : (kk == 2) ? af.z : af.w;
                acc[i][0] = fmaf(a, wfA[kk].x, acc[i][0]);
                acc[i][1] = fmaf(a, wfA[kk].y, acc[i][1]);
                acc[i][2] = fmaf(a, wfA[kk].z, acc[i][2]);
                acc[i][3] = fmaf(a, wfA[kk].w, acc[i][3]);
                acc[i][4] = fmaf(a, wfB[kk].x, acc[i][4]);
                acc[i][5] = fmaf(a, wfB[kk].y, acc[i][5]);
                acc[i][6] = fmaf(a, wfB[kk].z, acc[i][6]);
                acc[i][7] = fmaf(a, wfB[kk].w, acc[i][7]);
            }
        }
    }

    // epilogue: bias+relu, run-length over the thread's 8 stride-16 nodes
    // (batch sorted -> gidx monotone), LDS graph slots, few global atomics
    int nbase = bx * 128;
    int gbase = batch[nbase];                          // block-uniform
    int gidx[8];
#pragma unroll
    for (int i = 0; i < 8; ++i) {
        int node = nbase + my + i * 16;
        gidx[i] = (node < NN) ? batch[node] : -1;
    }

#pragma unroll
    for (int j = 0; j < 8; ++j) {
        int c = (j < 4) ? (c0 + j) : (64 + c0 + j - 4);
        float bb = b2[c];
        int run_g = -1;
        float rs = 0.f;
#pragma unroll
        for (int i = 0; i < 8; ++i) {
            if (gidx[i] < 0) break;
            float hcur = fmaxf(acc[i][j] + bb, 0.f);
            if (gidx[i] != run_g) {
                if (run_g >= 0) {
                    int slot = run_g - gbase;
                    if (slot < 4) atomicAdd(&lpool[slot * C_H2 + c], rs);
                    else          atomicAdd(&pooled[(run_g << 7) + c], rs);
                }
                run_g = gidx[i]; rs = hcur;
            } else {
                rs += hcur;
            }
        }
        if (run_g >= 0) {
            int slot = run_g - gbase;
            if (slot < 4) atomicAdd(&lpool[slot * C_H2 + c], rs);
            else          atomicAdd(&pooled[(run_g << 7) + c], rs);
        }
    }
    __syncthreads();
    for (int i = tid; i < 4 * C_H2; i += 256) {
        int slot = i >> 7, c = i & 127;
        int g = gbase + slot;
        float v = lpool[i];
        if (g < NG && v != 0.f) atomicAdd(&pooled[(g << 7) + c], v);
    }
}

// ---------------- FC: out = (pooled/cnt) @ Wfc + bfc ----------------
__device__ __forceinline__ int lower_bound(const int* __restrict__ a, int n, int key) {
    int lo = 0, hi = n;
    while (lo < hi) { int mid = (lo + hi) >> 1; if (a[mid] < key) lo = mid + 1; else hi = mid; }
    return lo;
}

__global__ void k_fc(const float* __restrict__ pooled, const int* __restrict__ batch,
                     const float* __restrict__ Wfc, const float* __restrict__ bfc,
                     float* __restrict__ out) {
    int t = blockIdx.x * blockDim.x + threadIdx.x;
    if (t >= NG * C_OUT) return;
    int g = t >> 1, o = t & 1;
    int start = lower_bound(batch, NN, g);
    int end   = lower_bound(batch, NN, g + 1);
    float inv = 1.f / fmaxf((float)(end - start), 1.f);
    float s = bfc[o];
    for (int cc = 0; cc < C_H2; ++cc)
        s = fmaf(pooled[(g << 7) + cc] * inv, Wfc[cc * C_OUT + o], s);
    out[t] = s;
}

extern "C" void kernel_launch(void* const* d_in, const int* in_sizes, int n_in,
                              void* d_out, int out_size, void* d_ws, size_t ws_size,
                              hipStream_t stream) {
    const float* x     = (const float*)d_in[0];
    const int*   ei    = (const int*)d_in[1];   // [2, E]: row0 = src, row1 = dst
    const int*   batch = (const int*)d_in[2];
    const float* W1    = (const float*)d_in[3];
    const float* b1    = (const float*)d_in[4];
    const float* W2    = (const float*)d_in[5];
    const float* b2    = (const float*)d_in[6];
    const float* Wfc   = (const float*)d_in[7];
    const float* bfc   = (const float*)d_in[8];
    float* out = (float*)d_out;

    // workspace carve-out (~52 MB)
    char* p = (char*)d_ws;
    auto alloc = [&](size_t bytes) { char* r = p; p += (bytes + 255) & ~size_t(255); return r; };
    float*  dinv    = (float*) alloc((size_t)NN * 4);
    int*    row_ptr = (int*)   alloc((size_t)(NN + 1) * 4);
    int*    btot    = (int*)   alloc((size_t)NB * 4);
    int*    bbase   = (int*)   alloc((size_t)(NB + 1) * 4);
    int*    hist    = (int*)   alloc((size_t)NB * PCHUNKS * 4);
    int*    offs    = (int*)   alloc((size_t)NB * PCHUNKS * 4);
    int2*   ed2     = (int2*)  alloc((size_t)NE * 8);
    int*    ed      = (int*)   alloc((size_t)NE * 4);
    float4* x4      = (float4*)alloc((size_t)NN * 16);
    float4* aggx4   = (float4*)alloc((size_t)NN * 16);
    float*  agg1    = (float*) alloc((size_t)(NN + 128) * C_H1 * 4);  // padded
    float*  pooled  = (float*) alloc((size_t)NG * C_H2 * 4);

    hipMemsetAsync(pooled, 0, (size_t)NG * C_H2 * 4, stream);
    k_hist    <<<PCHUNKS, 256, 0, stream>>>(ei, hist);
    k_colscan0<<<NB, 256, 0, stream>>>(hist, offs, btot);
    k_bbase   <<<1, 256, 0, stream>>>(btot, bbase, row_ptr);
    k_scatterA<<<PCHUNKS, 256, 0, stream>>>(ei, offs, bbase, ed2);
    k_B1      <<<NB, 256, 0, stream>>>(ed2, bbase, dinv, row_ptr);
    k_x4      <<<(NN + 255) / 256, 256, 0, stream>>>(x, x4);
    k_scatterB<<<NB, 256, 0, stream>>>(row_ptr, ed2, dinv, x4, ed, aggx4);
    k_edge1   <<<MM2_PAD * 32, 256, 0, stream>>>(row_ptr, ed, aggx4, W1, b1, agg1);
    k_mm2pool <<<MM2_PAD, 256, 0, stream>>>(agg1, W2, b2, batch, pooled);
    k_fc      <<<(NG * C_OUT + 255) / 256, 256, 0, stream>>>(pooled, batch, Wfc, bfc, out);
}

// Round 7
// 233.122 us; speedup vs baseline: 1.0189x; 1.0189x over previous
//
#include <hip/hip_runtime.h>

#define NN 100000     // nodes
#define NE 1600000    // edges
#define NG 512        // graphs
#define C_H1 64
#define C_H2 128
#define C_OUT 2

#define MM2_BLOCKS ((NN + 127) / 128)                 // 782 (128 nodes/block)
#define NB ((NN + 255) >> 8)                          // 391 dst-buckets of 256 nodes
#define PCHUNKS 512                                   // partition chunks
#define PCHUNK_E (NE / PCHUNKS)                       // 3125 edges per chunk
#define AT_S 68                                       // A-tile row stride (16B-aligned, non-pow2)

// ---------------- radix partition phase 1: per-chunk bucket histograms -----------
__global__ void k_hist(const int* __restrict__ ei, int* __restrict__ hist) {
    __shared__ int lh[NB];
    int tid = threadIdx.x;
    int blk = blockIdx.x;
    for (int i = tid; i < NB; i += 256) lh[i] = 0;
    __syncthreads();
    int base = blk * PCHUNK_E;
    for (int e = base + tid; e < base + PCHUNK_E; e += 256)
        atomicAdd(&lh[ei[NE + e] >> 8], 1);
    __syncthreads();
    for (int i = tid; i < NB; i += 256) hist[i * PCHUNKS + blk] = lh[i];
}

// ---------------- phase 2a: per-bucket scan over chunks (bucket-relative) --------
__global__ void k_colscan0(const int* __restrict__ hist, int* __restrict__ offs,
                           int* __restrict__ btot) {
    __shared__ int sh[256];
    int b = blockIdx.x;
    int tid = threadIdx.x;
    int v0 = hist[b * PCHUNKS + 2 * tid];
    int v1 = hist[b * PCHUNKS + 2 * tid + 1];
    sh[tid] = v0 + v1;
    __syncthreads();
    for (int off = 1; off < 256; off <<= 1) {
        int v = (tid >= off) ? sh[tid - off] : 0;
        __syncthreads();
        sh[tid] += v;
        __syncthreads();
    }
    int base = (tid == 0) ? 0 : sh[tid - 1];
    offs[b * PCHUNKS + 2 * tid]     = base;
    offs[b * PCHUNKS + 2 * tid + 1] = base + v0;
    if (tid == 255) btot[b] = sh[255];
}

// ---------------- phase 2b: exclusive scan of 391 bucket totals ------------------
__global__ void k_bbase(const int* __restrict__ btot, int* __restrict__ bbase,
                        int* __restrict__ row_ptr) {
    __shared__ int sh[256];
    int tid = threadIdx.x;
    int v0 = (2 * tid     < NB) ? btot[2 * tid]     : 0;
    int v1 = (2 * tid + 1 < NB) ? btot[2 * tid + 1] : 0;
    sh[tid] = v0 + v1;
    __syncthreads();
    for (int off = 1; off < 256; off <<= 1) {
        int v = (tid >= off) ? sh[tid - off] : 0;
        __syncthreads();
        sh[tid] += v;
        __syncthreads();
    }
    int base = (tid == 0) ? 0 : sh[tid - 1];
    if (2 * tid     < NB) bbase[2 * tid]     = base;
    if (2 * tid + 1 < NB) bbase[2 * tid + 1] = base + v0;
    if (tid == 255) { bbase[NB] = sh[255]; row_ptr[NN] = sh[255]; }   // == NE
}

// ---------------- phase 3: scatter via LDS cursors (no global atomics) -----------
__global__ void k_scatterA(const int* __restrict__ ei, const int* __restrict__ offs,
                           const int* __restrict__ bbase, int2* __restrict__ ed2) {
    __shared__ int lcur[NB];
    int tid = threadIdx.x;
    int blk = blockIdx.x;
    for (int i = tid; i < NB; i += 256) lcur[i] = bbase[i] + offs[i * PCHUNKS + blk];
    __syncthreads();
    int base = blk * PCHUNK_E;
    for (int e = base + tid; e < base + PCHUNK_E; e += 256) {
        int s = ei[e], d = ei[NE + e];
        int pos = atomicAdd(&lcur[d >> 8], 1);     // LDS atomic, low contention
        int2 v; v.x = s; v.y = d;
        ed2[pos] = v;
    }
}

// ---------------- B1: bucket-local degree -> dinv + row_ptr (no global atomics) --
__global__ void k_B1(const int2* __restrict__ ed2, const int* __restrict__ bbase,
                     float* __restrict__ dinv, int* __restrict__ row_ptr) {
    __shared__ int ldeg[256];
    __shared__ int sh[256];
    int b = blockIdx.x;
    int tid = threadIdx.x;
    int lo = b << 8;
    ldeg[tid] = 0;
    __syncthreads();
    int beg = bbase[b], end = bbase[b + 1];
    for (int j = beg + tid; j < end; j += 256)
        atomicAdd(&ldeg[ed2[j].y - lo], 1);
    __syncthreads();
    int d = ldeg[tid];
    int node = lo + tid;
    if (node < NN) dinv[node] = rsqrtf((float)d + 1.0f);
    sh[tid] = d;
    __syncthreads();
    for (int off = 1; off < 256; off <<= 1) {
        int v = (tid >= off) ? sh[tid - off] : 0;
        __syncthreads();
        sh[tid] += v;
        __syncthreads();
    }
    int excl = beg + ((tid == 0) ? 0 : sh[tid - 1]);
    if (node < NN) row_ptr[node] = excl;
}

// ---------------- repack x to float4 rows (16B gathers downstream) ---------------
__global__ void k_x4(const float* __restrict__ x, float4* __restrict__ x4) {
    int n = blockIdx.x * blockDim.x + threadIdx.x;
    if (n >= NN) return;
    float4 v; v.x = x[n * 3]; v.y = x[n * 3 + 1]; v.z = x[n * 3 + 2]; v.w = 0.f;
    x4[n] = v;
}

// ---------------- scatter pass B + fused layer-1 aggregation ---------------------
// ed is just the src index (4B): nrm is recomputed in k_edge1 from
// aggx4[src].w (= dinv[src], packed here) * dinv[dst] -- identical fp multiply,
// so agg1 stays bitwise identical while ed traffic halves.
__global__ void k_scatterB(const int* __restrict__ row_ptr, const int2* __restrict__ ed2,
                           const float* __restrict__ dinv, const float4* __restrict__ x4,
                           int* __restrict__ ed, float4* __restrict__ aggx4) {
    __shared__ int   lcur[256];
    __shared__ float ldin[256];
    __shared__ float lax[256 * 3];
    int b = blockIdx.x;
    int lo = b << 8;
    int tid = threadIdx.x;
    int node = lo + tid;
    if (node <= NN) lcur[tid] = row_ptr[node < NN ? node : NN];
    else            lcur[tid] = 0;
    ldin[tid] = (node < NN) ? dinv[node] : 0.f;
    lax[tid] = 0.f; lax[256 + tid] = 0.f; lax[512 + tid] = 0.f;
    __syncthreads();
    int seg_beg = row_ptr[lo];
    int hi = lo + 256; if (hi > NN) hi = NN;
    int seg_end = row_ptr[hi];
    for (int j = seg_beg + tid; j < seg_end; j += 256) {
        int2 sd = ed2[j];
        int local = sd.y - lo;
        int pos = atomicAdd(&lcur[local], 1);
        float nrm = dinv[sd.x] * ldin[local];
        ed[pos] = sd.x;                                // 4B scatter
        float4 xs = x4[sd.x];                          // 16B gather, L2-hot (1.6MB)
        atomicAdd(&lax[local],       nrm * xs.x);      // ds_add_f32
        atomicAdd(&lax[256 + local], nrm * xs.y);
        atomicAdd(&lax[512 + local], nrm * xs.z);
    }
    __syncthreads();
    if (node < NN) {
        float di = ldin[tid];
        float s2 = di * di;
        float4 xs = x4[node];
        float4 a;
        a.x = lax[tid]       + s2 * xs.x;
        a.y = lax[256 + tid] + s2 * xs.y;
        a.z = lax[512 + tid] + s2 * xs.z;
        a.w = di;                                      // pack dinv for k_edge1
        aggx4[node] = a;
    }
}

// ---------------- layer 2 aggregate via on-the-fly h1 recompute ------------------
// (v9's XCD swizzle reverted: FETCH/dur unchanged -- mapping assumption falsified)
__global__ void k_edge1(const int* __restrict__ row_ptr, const int* __restrict__ ed,
                        const float4* __restrict__ aggx4,
                        const float* __restrict__ W1, const float* __restrict__ b1,
                        float* __restrict__ agg1) {
    __shared__ float4 lp[256];                        // 64 per wave
    int t = blockIdx.x * 256 + threadIdx.x;           // grid exact: NN*64/256
    int n = t >> 6, c = t & 63;
    int lane = threadIdx.x & 63;
    int wbase = threadIdx.x & 192;                    // wave's LDS base (0,64,128,192)

    float w0 = W1[c], w1 = W1[64 + c], w2 = W1[128 + c], bb = b1[c];
    float4 an = aggx4[n];                             // wave-uniform
    float di = an.w;                                  // dinv[n], packed by scatterB
    float hself = fmaxf(fmaf(an.x, w0, fmaf(an.y, w1, fmaf(an.z, w2, bb))), 0.f);
    float acc = di * di * hself;

    int beg = row_ptr[n], end = row_ptr[n + 1];
    for (int base = beg; base < end; base += 64) {
        int m = end - base; if (m > 64) m = 64;
        if (lane < m) {
            int s = ed[base + lane];                  // coalesced 4B
            float4 ax = aggx4[s];                     // random 16B, L2-hot
            float4 p; p.x = ax.x; p.y = ax.y; p.z = ax.z; p.w = ax.w * di;  // nrm
            lp[wbase + lane] = p;
        }
        int e = 0;
        for (; e + 3 < m; e += 4) {
            float4 p0 = lp[wbase + e];
            float4 p1 = lp[wbase + e + 1];
            float4 p2 = lp[wbase + e + 2];
            float4 p3 = lp[wbase + e + 3];
            float h0  = fmaxf(fmaf(p0.x, w0, fmaf(p0.y, w1, fmaf(p0.z, w2, bb))), 0.f);
            float h1v = fmaxf(fmaf(p1.x, w0, fmaf(p1.y, w1, fmaf(p1.z, w2, bb))), 0.f);
            float h2v = fmaxf(fmaf(p2.x, w0, fmaf(p2.y, w1, fmaf(p2.z, w2, bb))), 0.f);
            float h3v = fmaxf(fmaf(p3.x, w0, fmaf(p3.y, w1, fmaf(p3.z, w2, bb))), 0.f);
            acc = fmaf(p0.w, h0, acc);
            acc = fmaf(p1.w, h1v, acc);
            acc = fmaf(p2.w, h2v, acc);
            acc = fmaf(p3.w, h3v, acc);
        }
        for (; e < m; ++e) {
            float4 p = lp[wbase + e];
            float h = fmaxf(fmaf(p.x, w0, fmaf(p.y, w1, fmaf(p.z, w2, bb))), 0.f);
            acc = fmaf(p.w, h, acc);
        }
    }
    agg1[t] = acc;   // NO bias/relu here: h2 = relu(agg1 @ W2 + b2)
}

// ---------------- fused register-tiled GEMM + pool (v10: split resources) ---------
// Six-variant ledger (42-55us, VALUBusy<=43%): every prior shape either paid a
// ~200-900cy agg1 miss INSIDE the k-loop (v7-v9), or put W2+A on the one LDS
// pipe with 2-3 blocks/CU + barrier convoys (v3/v6). v10 splits the resources:
//   A-tile  -> LDS, staged ONCE per block (pipelined coalesced rounds; latency
//              paid at the stage, not per-k0), conflict-free v6 geometry
//              (stride-16 rows, AT_S=68, 4-address broadcast reads).
//   W2      -> direct global. 32KB read-only = exactly L1-sized, shared by all
//              blocks -> L1-hot. Halves the LDS-pipe load (8 b128/wave/k0) and
//              frees 32KB LDS: 37KB total -> 4 blocks/CU.
// No global dependence inside the k-loop; ONE barrier. FMA order unchanged
// (k ascending) -> bitwise-identical output. No min-occupancy bound (r1 lesson).
__global__ __launch_bounds__(256)
void k_mm2pool(const float* __restrict__ agg1, const float* __restrict__ W2,
               const float* __restrict__ b2, const int* __restrict__ batch,
               float* __restrict__ pooled) {
    __shared__ float at[128 * AT_S];      // 34 KiB: full 128x64 A-tile
    __shared__ float lpool[4 * C_H2];     // 2 KiB
    int tid = threadIdx.x;
    int bx  = blockIdx.x;

    const float4* a4 = (const float4*)(agg1 + (size_t)bx * 128 * C_H1);
    for (int i = tid; i < 128 * 16; i += 256) {       // stage A once, coalesced
        int row = i >> 4, q = i & 15;
        *(float4*)&at[row * AT_S + q * 4] = a4[i];
    }
    for (int i = tid; i < 4 * C_H2; i += 256) lpool[i] = 0.f;
    __syncthreads();                       // the ONLY pre-epilogue barrier

    int tx = tid & 15;            // channel group
    int my = tid >> 4;            // node lane: rows my, my+16, ..., my+112
    int c0 = tx * 4;              // low ch group c0..c0+3; high group 64+c0..+3

    float acc[8][8];
#pragma unroll
    for (int i = 0; i < 8; ++i)
#pragma unroll
        for (int j = 0; j < 8; ++j) acc[i][j] = 0.f;

#pragma unroll 1
    for (int k0 = 0; k0 < C_H1; k0 += 4) {
        float4 wfA[4], wfB[4];
#pragma unroll
        for (int kk = 0; kk < 4; ++kk) {              // global W2: L1-hot broadcast
            wfA[kk] = *(const float4*)&W2[(k0 + kk) * C_H2 + c0];
            wfB[kk] = *(const float4*)&W2[(k0 + kk) * C_H2 + 64 + c0];
        }
#pragma unroll
        for (int i = 0; i < 8; ++i) {
            float4 af = *(const float4*)&at[(my + i * 16) * AT_S + k0];  // LDS bcast
#pragma unroll
            for (int kk = 0; kk < 4; ++kk) {
                float a = (kk == 0) ? af.x : (kk == 1) ? af.y : (kk == 2) ? af.z : af.w;
                acc[i][0] = fmaf(a, wfA[kk].x, acc[i][0]);
                acc[i][1] = fmaf(a, wfA[kk].y, acc[i][1]);
                acc[i][2] = fmaf(a, wfA[kk].z, acc[i][2]);
                acc[i][3] = fmaf(a, wfA[kk].w, acc[i][3]);
                acc[i][4] = fmaf(a, wfB[kk].x, acc[i][4]);
                acc[i][5] = fmaf(a, wfB[kk].y, acc[i][5]);
                acc[i][6] = fmaf(a, wfB[kk].z, acc[i][6]);
                acc[i][7] = fmaf(a, wfB[kk].w, acc[i][7]);
            }
        }
    }

    // epilogue: bias+relu, run-length over the thread's 8 stride-16 nodes
    // (batch sorted -> gidx monotone), LDS graph slots, few global atomics
    int nbase = bx * 128;
    int gbase = batch[nbase];                          // block-uniform
    int gidx[8];
#pragma unroll
    for (int i = 0; i < 8; ++i) {
        int node = nbase + my + i * 16;
        gidx[i] = (node < NN) ? batch[node] : -1;
    }

#pragma unroll
    for (int j = 0; j < 8; ++j) {
        int c = (j < 4) ? (c0 + j) : (64 + c0 + j - 4);
        float bb = b2[c];
        int run_g = -1;
        float rs = 0.f;
#pragma unroll
        for (int i = 0; i < 8; ++i) {
            if (gidx[i] < 0) break;
            float hcur = fmaxf(acc[i][j] + bb, 0.f);
            if (gidx[i] != run_g) {
                if (run_g >= 0) {
                    int slot = run_g - gbase;
                    if (slot < 4) atomicAdd(&lpool[slot * C_H2 + c], rs);
                    else          atomicAdd(&pooled[(run_g << 7) + c], rs);
                }
                run_g = gidx[i]; rs = hcur;
            } else {
                rs += hcur;
            }
        }
        if (run_g >= 0) {
            int slot = run_g - gbase;
            if (slot < 4) atomicAdd(&lpool[slot * C_H2 + c], rs);
            else          atomicAdd(&pooled[(run_g << 7) + c], rs);
        }
    }
    __syncthreads();
    for (int i = tid; i < 4 * C_H2; i += 256) {
        int slot = i >> 7, c = i & 127;
        int g = gbase + slot;
        float v = lpool[i];
        if (g < NG && v != 0.f) atomicAdd(&pooled[(g << 7) + c], v);
    }
}

// ---------------- FC: out = (pooled/cnt) @ Wfc + bfc ----------------
__device__ __forceinline__ int lower_bound(const int* __restrict__ a, int n, int key) {
    int lo = 0, hi = n;
    while (lo < hi) { int mid = (lo + hi) >> 1; if (a[mid] < key) lo = mid + 1; else hi = mid; }
    return lo;
}

__global__ void k_fc(const float* __restrict__ pooled, const int* __restrict__ batch,
                     const float* __restrict__ Wfc, const float* __restrict__ bfc,
                     float* __restrict__ out) {
    int t = blockIdx.x * blockDim.x + threadIdx.x;
    if (t >= NG * C_OUT) return;
    int g = t >> 1, o = t & 1;
    int start = lower_bound(batch, NN, g);
    int end   = lower_bound(batch, NN, g + 1);
    float inv = 1.f / fmaxf((float)(end - start), 1.f);
    float s = bfc[o];
    for (int cc = 0; cc < C_H2; ++cc)
        s = fmaf(pooled[(g << 7) + cc] * inv, Wfc[cc * C_OUT + o], s);
    out[t] = s;
}

extern "C" void kernel_launch(void* const* d_in, const int* in_sizes, int n_in,
                              void* d_out, int out_size, void* d_ws, size_t ws_size,
                              hipStream_t stream) {
    const float* x     = (const float*)d_in[0];
    const int*   ei    = (const int*)d_in[1];   // [2, E]: row0 = src, row1 = dst
    const int*   batch = (const int*)d_in[2];
    const float* W1    = (const float*)d_in[3];
    const float* b1    = (const float*)d_in[4];
    const float* W2    = (const float*)d_in[5];
    const float* b2    = (const float*)d_in[6];
    const float* Wfc   = (const float*)d_in[7];
    const float* bfc   = (const float*)d_in[8];
    float* out = (float*)d_out;

    // workspace carve-out (~52 MB)
    char* p = (char*)d_ws;
    auto alloc = [&](size_t bytes) { char* r = p; p += (bytes + 255) & ~size_t(255); return r; };
    float*  dinv    = (float*) alloc((size_t)NN * 4);
    int*    row_ptr = (int*)   alloc((size_t)(NN + 1) * 4);
    int*    btot    = (int*)   alloc((size_t)NB * 4);
    int*    bbase   = (int*)   alloc((size_t)(NB + 1) * 4);
    int*    hist    = (int*)   alloc((size_t)NB * PCHUNKS * 4);
    int*    offs    = (int*)   alloc((size_t)NB * PCHUNKS * 4);
    int2*   ed2     = (int2*)  alloc((size_t)NE * 8);
    int*    ed      = (int*)   alloc((size_t)NE * 4);
    float4* x4      = (float4*)alloc((size_t)NN * 16);
    float4* aggx4   = (float4*)alloc((size_t)NN * 16);
    float*  agg1    = (float*) alloc((size_t)(NN + 128) * C_H1 * 4);  // padded
    float*  pooled  = (float*) alloc((size_t)NG * C_H2 * 4);

    hipMemsetAsync(pooled, 0, (size_t)NG * C_H2 * 4, stream);
    k_hist    <<<PCHUNKS, 256, 0, stream>>>(ei, hist);
    k_colscan0<<<NB, 256, 0, stream>>>(hist, offs, btot);
    k_bbase   <<<1, 256, 0, stream>>>(btot, bbase, row_ptr);
    k_scatterA<<<PCHUNKS, 256, 0, stream>>>(ei, offs, bbase, ed2);
    k_B1      <<<NB, 256, 0, stream>>>(ed2, bbase, dinv, row_ptr);
    k_x4      <<<(NN + 255) / 256, 256, 0, stream>>>(x, x4);
    k_scatterB<<<NB, 256, 0, stream>>>(row_ptr, ed2, dinv, x4, ed, aggx4);
    k_edge1   <<<(NN * C_H1) / 256, 256, 0, stream>>>(row_ptr, ed, aggx4, W1, b1, agg1);
    k_mm2pool <<<MM2_BLOCKS, 256, 0, stream>>>(agg1, W2, b2, batch, pooled);
    k_fc      <<<(NG * C_OUT + 255) / 256, 256, 0, stream>>>(pooled, batch, Wfc, bfc, out);
}